// Round 3
// baseline (36644.193 us; speedup 1.0000x reference)
//
#include <hip/hip_runtime.h>
#include <hip/hip_bf16.h>

// Problem constants
#define BB 128   // batch
#define TT 1024  // timesteps
#define HH 512   // hidden
#define VV 256   // vocab
#define RS 520   // LDS row stride in bf16 (512 + 8 pad -> 1040 B, uniform banks)
#define NBLK 128 // persistent grid: 64 layer1 + 64 layer2 blocks

typedef __attribute__((ext_vector_type(8))) short short8;   // 8 x bf16
typedef __attribute__((ext_vector_type(4))) float floatx4;  // MFMA acc

__device__ __forceinline__ floatx4 mfma16(short8 a, short8 b, floatx4 c) {
    return __builtin_amdgcn_mfma_f32_16x16x32_bf16(a, b, c, 0, 0, 0);
}
__device__ __forceinline__ float sigm(float x) { return 1.0f / (1.0f + __expf(-x)); }
__device__ __forceinline__ float tanh_fast(float x) {
    return 2.0f / (1.0f + __expf(-2.0f * x)) - 1.0f;   // saturates correctly
}

// One-shot canonicalization: fp32 weights -> bf16 ws copies; bias pre-sums; x transpose.
__global__ __launch_bounds__(256) void canon(
    const float* __restrict__ x,
    const float* __restrict__ Whh1, const float* __restrict__ Wih2,
    const float* __restrict__ Whh2, const float* __restrict__ Wlin,
    const float* __restrict__ bih1, const float* __restrict__ bhh1,
    const float* __restrict__ bih2, const float* __restrict__ bhh2,
    __hip_bfloat16* __restrict__ Whh1c, __hip_bfloat16* __restrict__ Wih2c,
    __hip_bfloat16* __restrict__ Whh2c, __hip_bfloat16* __restrict__ Wlinc,
    float* __restrict__ bsum1, float* __restrict__ bsum2,
    float* __restrict__ xT)
{
    const int tid = blockIdx.x * 256 + threadIdx.x;
    const int np  = gridDim.x * 256;
    for (int i = tid; i < 2048 * 512; i += np) {
        Whh1c[i] = __float2bfloat16(Whh1[i]);
        Wih2c[i] = __float2bfloat16(Wih2[i]);
        Whh2c[i] = __float2bfloat16(Whh2[i]);
    }
    for (int i = tid; i < 256 * 512; i += np) Wlinc[i] = __float2bfloat16(Wlin[i]);
    for (int i = tid; i < 2048; i += np) {
        bsum1[i] = bih1[i] + bhh1[i];
        bsum2[i] = bih2[i] + bhh2[i];
    }
    for (int i = tid; i < BB * TT; i += np) {          // x[b][t] -> xT[t][b]
        int b = i >> 10, t = i & 1023;
        xT[t * BB + b] = x[i];
    }
}

// Persistent 2-stage pipelined LSTM. Blocks [0,64): layer1; [64,128): layer2.
// Each block holds its weight slice in LDS (64 gate-rows x 512 k, padded).
// Grid barrier per step: one counter per step (zeroed by host memset), device
// scope atomics + __threadfence release/acquire (G16 cross-XCD idiom).
// Step s: stage1 computes h1(s) (s<TT); stage2 computes h2(s-1) (s>=1) and
// streams it into the output slot (b*T + t2) as 512 bf16 (= row's final 1KB).
__global__ __launch_bounds__(256) void lstm_persist(
    const float* __restrict__ xT,              // [T][B] fp32
    const float* __restrict__ Wih1,            // [2048] fp32 (IN=1)
    const __hip_bfloat16* __restrict__ Whh1c,  // [2048,512] bf16
    const float* __restrict__ bsum1,           // [2048]
    const __hip_bfloat16* __restrict__ Wih2c,  // [2048,512] bf16
    const __hip_bfloat16* __restrict__ Whh2c,  // [2048,512] bf16
    const float* __restrict__ bsum2,           // [2048]
    __hip_bfloat16* __restrict__ h1buf,        // [2][B*H] bf16
    __hip_bfloat16* __restrict__ h2st,         // [2][B*H] bf16
    float* __restrict__ c1, float* __restrict__ c2,  // [B*H] fp32
    __hip_bfloat16* __restrict__ h2slots,      // d_out viewed as bf16 slots
    unsigned* __restrict__ ctr)                // [TT+1] barrier counters
{
    extern __shared__ char smem[];
    __hip_bfloat16* LW0 = (__hip_bfloat16*)smem;               // 64 x RS
    __hip_bfloat16* LW1 = (__hip_bfloat16*)(smem + 64 * RS * 2);

    const int bid   = blockIdx.x;
    const int stage = bid >> 6;
    const int lb    = bid & 63;
    const int j0    = (lb & 31) * 16;          // h-unit tile
    const int b0    = (lb >> 5) * 64;          // batch tile
    const int w     = threadIdx.x >> 6;
    const int lane  = threadIdx.x & 63;
    const int q     = lane >> 4, ln = lane & 15;
    const int r0    = b0 + w * 16;
    const size_t BH = (size_t)BB * HH;

    // ---- load weight slice(s) into LDS (once) ----
    {
        const __hip_bfloat16* S0 = (stage == 0) ? Whh1c : Wih2c;
        for (int idx = threadIdx.x; idx < 64 * 64; idx += 256) {
            const int nr = idx >> 6, ch = idx & 63;          // row-in-slice, 16B chunk
            const int g = nr >> 4, i = nr & 15;
            const size_t grow = (size_t)(g * 512 + j0 + i) * 512;
            *(float4*)((char*)LW0 + nr * (RS * 2) + ch * 16) =
                *(const float4*)(S0 + grow + ch * 8);
            if (stage == 1)
                *(float4*)((char*)LW1 + nr * (RS * 2) + ch * 16) =
                    *(const float4*)(Whh2c + grow + ch * 8);
        }
    }
    __syncthreads();

    const int arow = (r0 + ln) * HH + q * 8;   // A[m=ln][k=q*8+j] byte base /2

    for (int s = 0; s <= TT; ++s) {
        if (stage == 0) {
            if (s < TT) {
                const __hip_bfloat16* hA = h1buf + (size_t)((s + 1) & 1) * BH;
                floatx4 acc[4];
                #pragma unroll
                for (int g = 0; g < 4; ++g) acc[g] = floatx4{0, 0, 0, 0};
                #pragma unroll
                for (int kk = 0; kk < 16; ++kk) {
                    short8 a = *(const short8*)(hA + arow + kk * 32);
                    #pragma unroll
                    for (int g = 0; g < 4; ++g)
                        acc[g] = mfma16(a, *(const short8*)(LW0 + (g * 16 + ln) * RS + kk * 32 + q * 8), acc[g]);
                }
                #pragma unroll
                for (int reg = 0; reg < 4; ++reg) {
                    const int b = r0 + q * 4 + reg;
                    const int j = j0 + ln;
                    const float xv = xT[s * BB + b];
                    float gi = acc[0][reg] + xv * Wih1[       j] + bsum1[       j];
                    float gf = acc[1][reg] + xv * Wih1[ 512 + j] + bsum1[ 512 + j];
                    float gg = acc[2][reg] + xv * Wih1[1024 + j] + bsum1[1024 + j];
                    float go = acc[3][reg] + xv * Wih1[1536 + j] + bsum1[1536 + j];
                    const int idx = b * HH + j;
                    float cnew = sigm(gf) * c1[idx] + sigm(gi) * tanh_fast(gg);
                    c1[idx] = cnew;
                    h1buf[(size_t)(s & 1) * BH + idx] =
                        __float2bfloat16(sigm(go) * tanh_fast(cnew));
                }
            }
        } else {
            if (s >= 1) {
                const __hip_bfloat16* hA = h1buf + (size_t)((s + 1) & 1) * BH; // h1(s-1)
                const __hip_bfloat16* hB = h2st  + (size_t)(s & 1) * BH;       // h2(s-2)
                floatx4 acc[4];
                #pragma unroll
                for (int g = 0; g < 4; ++g) acc[g] = floatx4{0, 0, 0, 0};
                #pragma unroll
                for (int kk = 0; kk < 16; ++kk) {
                    short8 a = *(const short8*)(hA + arow + kk * 32);
                    #pragma unroll
                    for (int g = 0; g < 4; ++g)
                        acc[g] = mfma16(a, *(const short8*)(LW0 + (g * 16 + ln) * RS + kk * 32 + q * 8), acc[g]);
                }
                #pragma unroll
                for (int kk = 0; kk < 16; ++kk) {
                    short8 a = *(const short8*)(hB + arow + kk * 32);
                    #pragma unroll
                    for (int g = 0; g < 4; ++g)
                        acc[g] = mfma16(a, *(const short8*)(LW1 + (g * 16 + ln) * RS + kk * 32 + q * 8), acc[g]);
                }
                const int t2 = s - 1;
                #pragma unroll
                for (int reg = 0; reg < 4; ++reg) {
                    const int b = r0 + q * 4 + reg;
                    const int j = j0 + ln;
                    float gi = acc[0][reg] + bsum2[       j];
                    float gf = acc[1][reg] + bsum2[ 512 + j];
                    float gg = acc[2][reg] + bsum2[1024 + j];
                    float go = acc[3][reg] + bsum2[1536 + j];
                    const int idx = b * HH + j;
                    float cnew = sigm(gf) * c2[idx] + sigm(gi) * tanh_fast(gg);
                    c2[idx] = cnew;
                    __hip_bfloat16 hb = __float2bfloat16(sigm(go) * tanh_fast(cnew));
                    h2st[(size_t)((s + 1) & 1) * BH + idx] = hb;
                    h2slots[((size_t)b * TT + t2) * HH + j] = hb;   // out slot (b,t2)
                }
            }
        }
        // ---- grid barrier (step s) ----
        __threadfence();                       // release this thread's stores (agent)
        __syncthreads();
        if (threadIdx.x == 0) {
            __hip_atomic_fetch_add(&ctr[s], 1u, __ATOMIC_RELEASE, __HIP_MEMORY_SCOPE_AGENT);
            while (__hip_atomic_load(&ctr[s], __ATOMIC_ACQUIRE, __HIP_MEMORY_SCOPE_AGENT) < NBLK)
                __builtin_amdgcn_s_sleep(2);
            __threadfence();                   // acquire: invalidate stale cached lines
        }
        __syncthreads();
    }
}

// In-place linear+softmax over all T*B rows. Slot r holds h2 row (512 bf16 =
// 1024 B); we overwrite it with 256 fp32 softmax probs (same 1024 B). Each
// wave reads/writes only its own 16 rows -> read-before-write is dataflow-safe.
__global__ __launch_bounds__(256) void lin_softmax(
    const __hip_bfloat16* __restrict__ Wlinc,  // [256,512] bf16
    const float* __restrict__ blin,            // [256] fp32
    float* out)                                // d_out; aliases the bf16 slots
{
    const __hip_bfloat16* slots = (const __hip_bfloat16*)out;
    const int w = threadIdx.x >> 6;
    const int lane = threadIdx.x & 63;
    const int q = lane >> 4, ln = lane & 15;
    const int r0 = blockIdx.x * 64 + w * 16;

    floatx4 acc[16];
    #pragma unroll
    for (int n = 0; n < 16; ++n) acc[n] = floatx4{0, 0, 0, 0};

    const size_t arow = (size_t)(r0 + ln) * HH + q * 8;
    #pragma unroll 4
    for (int kk = 0; kk < 16; ++kk) {
        short8 a = *(const short8*)(slots + arow + kk * 32);
        #pragma unroll
        for (int n = 0; n < 16; ++n) {
            short8 bf = *(const short8*)(Wlinc + (n * 16 + ln) * HH + kk * 32 + q * 8);
            acc[n] = mfma16(a, bf, acc[n]);
        }
    }

    float bl[16];
    #pragma unroll
    for (int n = 0; n < 16; ++n) bl[n] = blin[n * 16 + ln];

    #pragma unroll
    for (int reg = 0; reg < 4; ++reg) {
        float v[16];
        float mx = -3.4e38f;
        #pragma unroll
        for (int n = 0; n < 16; ++n) {
            v[n] = acc[n][reg] + bl[n];
            mx = fmaxf(mx, v[n]);
        }
        #pragma unroll
        for (int m = 1; m < 16; m <<= 1) mx = fmaxf(mx, __shfl_xor(mx, m));
        float sum = 0.0f;
        #pragma unroll
        for (int n = 0; n < 16; ++n) { v[n] = __expf(v[n] - mx); sum += v[n]; }
        #pragma unroll
        for (int m = 1; m < 16; m <<= 1) sum += __shfl_xor(sum, m);
        const float inv = 1.0f / sum;

        const int r = r0 + q * 4 + reg;        // r = b*T + t (slot index)
        #pragma unroll
        for (int n = 0; n < 16; ++n)
            out[(size_t)r * VV + n * 16 + ln] = v[n] * inv;
    }
}

extern "C" void kernel_launch(void* const* d_in, const int* in_sizes, int n_in,
                              void* d_out, int out_size, void* d_ws, size_t ws_size,
                              hipStream_t stream)
{
    const float* x     = (const float*)d_in[0];
    const float* W_ih1 = (const float*)d_in[1];
    const float* W_hh1 = (const float*)d_in[2];
    const float* b_ih1 = (const float*)d_in[3];
    const float* b_hh1 = (const float*)d_in[4];
    const float* W_ih2 = (const float*)d_in[5];
    const float* W_hh2 = (const float*)d_in[6];
    const float* b_ih2 = (const float*)d_in[7];
    const float* b_hh2 = (const float*)d_in[8];
    const float* W_lin = (const float*)d_in[9];
    const float* b_lin = (const float*)d_in[10];

    char* p = (char*)d_ws;
    const size_t BH = (size_t)BB * HH;
    float* c1 = (float*)p;                 p += BH * 4;
    float* c2 = (float*)p;                 p += BH * 4;
    __hip_bfloat16* h1buf = (__hip_bfloat16*)p; p += 2 * BH * 2;
    __hip_bfloat16* h2st  = (__hip_bfloat16*)p; p += 2 * BH * 2;
    unsigned* ctr = (unsigned*)p;          p += 8192;           // (TT+1)*4 rounded
    const size_t zbytes = (size_t)(p - (char*)d_ws);            // zero-init region
    float* bsum1 = (float*)p;              p += 2048 * 4;
    float* bsum2 = (float*)p;              p += 2048 * 4;
    float* xT    = (float*)p;              p += (size_t)BB * TT * 4;
    __hip_bfloat16* Whh1c = (__hip_bfloat16*)p; p += (size_t)2048 * 512 * 2;
    __hip_bfloat16* Wih2c = (__hip_bfloat16*)p; p += (size_t)2048 * 512 * 2;
    __hip_bfloat16* Whh2c = (__hip_bfloat16*)p; p += (size_t)2048 * 512 * 2;
    __hip_bfloat16* Wlinc = (__hip_bfloat16*)p; p += (size_t)256 * 512 * 2;
    // total ws use ~8 MB

    hipMemsetAsync(d_ws, 0, zbytes, stream);   // h/c state + barrier counters

    canon<<<dim3(512), dim3(256), 0, stream>>>(
        x, W_hh1, W_ih2, W_hh2, W_lin, b_ih1, b_hh1, b_ih2, b_hh2,
        Whh1c, Wih2c, Whh2c, Wlinc, bsum1, bsum2, xT);

    // 133,120 B dynamic LDS (> 64 KB default cap) — set attr every call (idempotent)
    const int smem_bytes = 2 * 64 * RS * 2;
    (void)hipFuncSetAttribute((const void*)lstm_persist,
                              hipFuncAttributeMaxDynamicSharedMemorySize, smem_bytes);

    lstm_persist<<<dim3(NBLK), dim3(256), smem_bytes, stream>>>(
        xT, W_ih1, Whh1c, bsum1, Wih2c, Whh2c, bsum2,
        h1buf, h2st, c1, c2, (__hip_bfloat16*)d_out, ctr);

    lin_softmax<<<dim3((TT * BB) / 64), dim3(256), 0, stream>>>(
        Wlinc, b_lin, (float*)d_out);
}

// Round 4
// 14104.689 us; speedup vs baseline: 2.5980x; 2.5980x over previous
//
#include <hip/hip_runtime.h>
#include <hip/hip_bf16.h>

// Problem constants
#define BB 128   // batch
#define TT 1024  // timesteps
#define HH 512   // hidden
#define VV 256   // vocab
#define NBLK 128 // persistent grid: 64 layer1 + 64 layer2 blocks

typedef __attribute__((ext_vector_type(8))) short short8;   // 8 x bf16
typedef __attribute__((ext_vector_type(4))) float floatx4;  // MFMA acc

union AFrag { unsigned long long u[2]; short8 s; };

__device__ __forceinline__ floatx4 mfma16(short8 a, short8 b, floatx4 c) {
    return __builtin_amdgcn_mfma_f32_16x16x32_bf16(a, b, c, 0, 0, 0);
}
__device__ __forceinline__ float sigm(float x) { return 1.0f / (1.0f + __expf(-x)); }
__device__ __forceinline__ float tanh_fast(float x) {
    return 2.0f / (1.0f + __expf(-2.0f * x)) - 1.0f;   // saturates correctly
}
__device__ __forceinline__ void vmcnt0() {
    asm volatile("s_waitcnt vmcnt(0)" ::: "memory");
}
// Agent-scope RELAXED atomics: route through the MALL coherence point with NO
// cache writeback/invalidate (the round-3 killer was acquire/release fences).
__device__ __forceinline__ unsigned long long ald64(const unsigned long long* p) {
    return __hip_atomic_load(p, __ATOMIC_RELAXED, __HIP_MEMORY_SCOPE_AGENT);
}
__device__ __forceinline__ void ast32(unsigned* p, unsigned v) {
    __hip_atomic_store(p, v, __ATOMIC_RELAXED, __HIP_MEMORY_SCOPE_AGENT);
}

// One-shot canonicalization: fp32 weights -> bf16 ws copies; bias pre-sums; x transpose.
__global__ __launch_bounds__(256) void canon(
    const float* __restrict__ x,
    const float* __restrict__ Whh1, const float* __restrict__ Wih2,
    const float* __restrict__ Whh2, const float* __restrict__ Wlin,
    const float* __restrict__ bih1, const float* __restrict__ bhh1,
    const float* __restrict__ bih2, const float* __restrict__ bhh2,
    __hip_bfloat16* __restrict__ Whh1c, __hip_bfloat16* __restrict__ Wih2c,
    __hip_bfloat16* __restrict__ Whh2c, __hip_bfloat16* __restrict__ Wlinc,
    float* __restrict__ bsum1, float* __restrict__ bsum2,
    float* __restrict__ xT)
{
    const int tid = blockIdx.x * 256 + threadIdx.x;
    const int np  = gridDim.x * 256;
    for (int i = tid; i < 2048 * 512; i += np) {
        Whh1c[i] = __float2bfloat16(Whh1[i]);
        Wih2c[i] = __float2bfloat16(Wih2[i]);
        Whh2c[i] = __float2bfloat16(Whh2[i]);
    }
    for (int i = tid; i < 256 * 512; i += np) Wlinc[i] = __float2bfloat16(Wlin[i]);
    for (int i = tid; i < 2048; i += np) {
        bsum1[i] = bih1[i] + bhh1[i];
        bsum2[i] = bih2[i] + bhh2[i];
    }
    for (int i = tid; i < BB * TT; i += np) {          // x[b][t] -> xT[t][b]
        int b = i >> 10, t = i & 1023;
        xT[t * BB + b] = x[i];
    }
}

// Persistent 2-stage pipelined LSTM. Blocks [0,64): layer1; [64,128): layer2.
// Weights LDS-resident in MFMA-fragment-permuted order (conflict-free b128).
// Cell state c in 4 VGPRs/thread. h1/h2 exchanged via agent-relaxed atomics
// (u32-packed bf16 pairs). Barrier: vmcnt(0) + relaxed add/spin, no fences.
__global__ __launch_bounds__(256) void lstm_persist(
    const float* __restrict__ xT,              // [T][B] fp32
    const float* __restrict__ Wih1,            // [2048] fp32 (IN=1)
    const __hip_bfloat16* __restrict__ Whh1c,  // [2048,512] bf16
    const float* __restrict__ bsum1,           // [2048]
    const __hip_bfloat16* __restrict__ Wih2c,  // [2048,512] bf16
    const __hip_bfloat16* __restrict__ Whh2c,  // [2048,512] bf16
    const float* __restrict__ bsum2,           // [2048]
    unsigned* __restrict__ h1buf,              // [2][B*H/2] u32 (packed bf16 x2)
    unsigned* __restrict__ h2st,               // [2][B*H/2] u32
    __hip_bfloat16* __restrict__ h2slots,      // d_out as bf16 slots [B][T][H]
    unsigned* __restrict__ ctr)                // [TT+1] barrier counters
{
    extern __shared__ __hip_bfloat16 lds[];    // stage0: 64 KB; stage1: 128 KB

    const int bid   = blockIdx.x;
    const int stage = bid >> 6;                // 0: LSTM layer1, 1: LSTM layer2
    const int lb    = bid & 63;
    const int j0    = (lb & 31) * 16;          // h-unit tile
    const int b0    = (lb >> 5) * 64;          // batch tile
    const int w     = threadIdx.x >> 6;
    const int lane  = threadIdx.x & 63;
    const int q     = lane >> 4, ln = lane & 15;
    const int r0    = b0 + w * 16;             // wave's 16 batch rows

    // ---- stage weights into LDS, fragment-permuted (once) ----
    // chunk idx=(g*16+kk)*64+lane64 holds W[g*512+j0+(idx&15)][kk*32+((idx>>4)&3)*8 ..+8]
    {
        const __hip_bfloat16* S0 = (stage == 0) ? Whh1c : Wih2c;
        for (int idx = threadIdx.x; idx < 4096; idx += 256) {
            const int g = idx >> 10, kk = (idx >> 6) & 15, l = idx & 63;
            const int lnt = l & 15, qt = l >> 4;
            const size_t src = (size_t)(g * 512 + j0 + lnt) * 512 + kk * 32 + qt * 8;
            *(float4*)(lds + idx * 8) = *(const float4*)(S0 + src);
            if (stage == 1)
                *(float4*)(lds + 32768 + idx * 8) = *(const float4*)(Whh2c + src);
        }
    }
    __syncthreads();

    // per-thread step-invariant epilogue constants
    float wv[4], bs[4];
    #pragma unroll
    for (int g = 0; g < 4; ++g) {
        const int j = g * 512 + j0 + ln;
        if (stage == 0) { wv[g] = Wih1[j]; bs[g] = bsum1[j]; }
        else            { wv[g] = 0.0f;    bs[g] = bsum2[j]; }
    }
    float cre[4] = {0.0f, 0.0f, 0.0f, 0.0f};   // cell state, register-resident

    const unsigned long long* h1u = (const unsigned long long*)h1buf;
    const unsigned long long* h2u = (const unsigned long long*)h2st;
    const int au = (r0 + ln) * 128 + q * 2;    // A-frag base in u64 units

    for (int s = 0; s <= TT; ++s) {
        const int parR = (s + 1) & 1;          // read parity (state after s-1)
        const int parW = s & 1;
        const bool active = (stage == 0) ? (s < TT) : (s >= 1);
        if (active) {
            floatx4 acc[4];
            #pragma unroll
            for (int g = 0; g < 4; ++g) acc[g] = floatx4{0, 0, 0, 0};

            // burst-load A fragments (h vectors) from MALL into registers
            AFrag A0[16];
            {
                const unsigned long long* pA = h1u + (size_t)parR * 16384;
                #pragma unroll
                for (int kk = 0; kk < 16; ++kk) {
                    A0[kk].u[0] = ald64(pA + au + kk * 8);
                    A0[kk].u[1] = ald64(pA + au + kk * 8 + 1);
                }
            }
            AFrag A1[16];
            if (stage == 1) {
                const unsigned long long* pB = h2u + (size_t)parW * 16384; // h2(s-2)
                #pragma unroll
                for (int kk = 0; kk < 16; ++kk) {
                    A1[kk].u[0] = ald64(pB + au + kk * 8);
                    A1[kk].u[1] = ald64(pB + au + kk * 8 + 1);
                }
            }

            #pragma unroll
            for (int kk = 0; kk < 16; ++kk) {
                #pragma unroll
                for (int g = 0; g < 4; ++g)
                    acc[g] = mfma16(A0[kk].s,
                        *(const short8*)(lds + ((g * 16 + kk) * 64 + lane) * 8), acc[g]);
            }
            if (stage == 1) {
                #pragma unroll
                for (int kk = 0; kk < 16; ++kk) {
                    #pragma unroll
                    for (int g = 0; g < 4; ++g)
                        acc[g] = mfma16(A1[kk].s,
                            *(const short8*)(lds + 32768 + ((g * 16 + kk) * 64 + lane) * 8), acc[g]);
                }
            }

            // epilogue: gates -> c,h ; pack bf16 pairs via lane-pair shuffle
            float4 xv4 = {0, 0, 0, 0};
            if (stage == 0) xv4 = *(const float4*)(xT + s * BB + r0 + q * 4);
            unsigned pk[4];
            #pragma unroll
            for (int reg = 0; reg < 4; ++reg) {
                const float xv = ((const float*)&xv4)[reg];
                float gi = acc[0][reg] + xv * wv[0] + bs[0];
                float gf = acc[1][reg] + xv * wv[1] + bs[1];
                float gg = acc[2][reg] + xv * wv[2] + bs[2];
                float go = acc[3][reg] + xv * wv[3] + bs[3];
                float cn = sigm(gf) * cre[reg] + sigm(gi) * tanh_fast(gg);
                cre[reg] = cn;
                float hn = sigm(go) * tanh_fast(cn);
                __hip_bfloat16 hb = __float2bfloat16(hn);
                unsigned short us; __builtin_memcpy(&us, &hb, 2);
                unsigned mine = us;
                unsigned other = (unsigned)__shfl_xor((int)mine, 1, 64);
                pk[reg] = (ln & 1) ? ((other & 0xffffu) | (mine << 16))
                                   : ((mine & 0xffffu) | (other << 16));
            }
            const int jc = j0 + (ln & ~1);          // even column of the pair
            const int rA = (ln & 1) ? 2 : 0;        // even lanes: regs 0,1; odd: 2,3
            const int bA = r0 + q * 4 + rA;
            if (stage == 0) {
                unsigned* dst = h1buf + (size_t)parW * 32768;   // h1(s)
                ast32(dst + ((bA * HH + jc) >> 1),       pk[rA]);
                ast32(dst + (((bA + 1) * HH + jc) >> 1), pk[rA + 1]);
            } else {
                unsigned* dst = h2st + (size_t)parR * 32768;    // h2(s-1)
                ast32(dst + ((bA * HH + jc) >> 1),       pk[rA]);
                ast32(dst + (((bA + 1) * HH + jc) >> 1), pk[rA + 1]);
                const int t2 = s - 1;
                unsigned* outs = (unsigned*)h2slots;            // plain cached stores
                outs[(((size_t)bA * TT + t2) * HH + jc) >> 1]       = pk[rA];
                outs[(((size_t)(bA + 1) * TT + t2) * HH + jc) >> 1] = pk[rA + 1];
            }
        }
        // ---- grid barrier (step s): no cache maintenance, MALL-ordered ----
        vmcnt0();                 // all my stores complete at coherence point
        __syncthreads();
        if (threadIdx.x == 0) {
            __hip_atomic_fetch_add(&ctr[s], 1u, __ATOMIC_RELAXED, __HIP_MEMORY_SCOPE_AGENT);
            while (__hip_atomic_load(&ctr[s], __ATOMIC_RELAXED, __HIP_MEMORY_SCOPE_AGENT) < NBLK)
                __builtin_amdgcn_s_sleep(1);
        }
        __syncthreads();
    }
}

// In-place linear+softmax over all T*B rows. Slot r holds h2 row (512 bf16 =
// 1024 B); overwritten with 256 fp32 probs (same 1024 B). Each wave touches
// only its own 16 rows -> read-before-write is dataflow-safe.
__global__ __launch_bounds__(256) void lin_softmax(
    const __hip_bfloat16* __restrict__ Wlinc,  // [256,512] bf16
    const float* __restrict__ blin,            // [256] fp32
    float* out)                                // d_out; aliases the bf16 slots
{
    const __hip_bfloat16* slots = (const __hip_bfloat16*)out;
    const int w = threadIdx.x >> 6;
    const int lane = threadIdx.x & 63;
    const int q = lane >> 4, ln = lane & 15;
    const int r0 = blockIdx.x * 64 + w * 16;

    floatx4 acc[16];
    #pragma unroll
    for (int n = 0; n < 16; ++n) acc[n] = floatx4{0, 0, 0, 0};

    const size_t arow = (size_t)(r0 + ln) * HH + q * 8;
    #pragma unroll 4
    for (int kk = 0; kk < 16; ++kk) {
        short8 a = *(const short8*)(slots + arow + kk * 32);
        #pragma unroll
        for (int n = 0; n < 16; ++n) {
            short8 bf = *(const short8*)(Wlinc + (n * 16 + ln) * HH + kk * 32 + q * 8);
            acc[n] = mfma16(a, bf, acc[n]);
        }
    }

    float bl[16];
    #pragma unroll
    for (int n = 0; n < 16; ++n) bl[n] = blin[n * 16 + ln];

    #pragma unroll
    for (int reg = 0; reg < 4; ++reg) {
        float v[16];
        float mx = -3.4e38f;
        #pragma unroll
        for (int n = 0; n < 16; ++n) {
            v[n] = acc[n][reg] + bl[n];
            mx = fmaxf(mx, v[n]);
        }
        #pragma unroll
        for (int m = 1; m < 16; m <<= 1) mx = fmaxf(mx, __shfl_xor(mx, m));
        float sum = 0.0f;
        #pragma unroll
        for (int n = 0; n < 16; ++n) { v[n] = __expf(v[n] - mx); sum += v[n]; }
        #pragma unroll
        for (int m = 1; m < 16; m <<= 1) sum += __shfl_xor(sum, m);
        const float inv = 1.0f / sum;

        const int r = r0 + q * 4 + reg;        // r = b*T + t (slot index)
        #pragma unroll
        for (int n = 0; n < 16; ++n)
            out[(size_t)r * VV + n * 16 + ln] = v[n] * inv;
    }
}

extern "C" void kernel_launch(void* const* d_in, const int* in_sizes, int n_in,
                              void* d_out, int out_size, void* d_ws, size_t ws_size,
                              hipStream_t stream)
{
    const float* x     = (const float*)d_in[0];
    const float* W_ih1 = (const float*)d_in[1];
    const float* W_hh1 = (const float*)d_in[2];
    const float* b_ih1 = (const float*)d_in[3];
    const float* b_hh1 = (const float*)d_in[4];
    const float* W_ih2 = (const float*)d_in[5];
    const float* W_hh2 = (const float*)d_in[6];
    const float* b_ih2 = (const float*)d_in[7];
    const float* b_hh2 = (const float*)d_in[8];
    const float* W_lin = (const float*)d_in[9];
    const float* b_lin = (const float*)d_in[10];

    char* p = (char*)d_ws;
    const size_t BH = (size_t)BB * HH;
    unsigned* h1buf = (unsigned*)p;        p += 2 * BH * 2;    // 256 KB (2 slots, packed)
    unsigned* h2st  = (unsigned*)p;        p += 2 * BH * 2;    // 256 KB
    unsigned* ctr   = (unsigned*)p;        p += 8192;          // (TT+1)*4 rounded
    const size_t zbytes = (size_t)(p - (char*)d_ws);
    float* bsum1 = (float*)p;              p += 2048 * 4;
    float* bsum2 = (float*)p;              p += 2048 * 4;
    float* xT    = (float*)p;              p += (size_t)BB * TT * 4;
    __hip_bfloat16* Whh1c = (__hip_bfloat16*)p; p += (size_t)2048 * 512 * 2;
    __hip_bfloat16* Wih2c = (__hip_bfloat16*)p; p += (size_t)2048 * 512 * 2;
    __hip_bfloat16* Whh2c = (__hip_bfloat16*)p; p += (size_t)2048 * 512 * 2;
    __hip_bfloat16* Wlinc = (__hip_bfloat16*)p; p += (size_t)256 * 512 * 2;
    // total ws use ~8 MB

    hipMemsetAsync(d_ws, 0, zbytes, stream);   // h state + barrier counters

    canon<<<dim3(512), dim3(256), 0, stream>>>(
        x, W_hh1, W_ih2, W_hh2, W_lin, b_ih1, b_hh1, b_ih2, b_hh2,
        Whh1c, Wih2c, Whh2c, Wlinc, bsum1, bsum2, xT);

    const int smem_bytes = 131072;   // 128 KB dynamic LDS (stage1 uses all of it)
    (void)hipFuncSetAttribute((const void*)lstm_persist,
                              hipFuncAttributeMaxDynamicSharedMemorySize, smem_bytes);

    lstm_persist<<<dim3(NBLK), dim3(256), smem_bytes, stream>>>(
        xT, W_ih1, Whh1c, bsum1, Wih2c, Whh2c, bsum2,
        h1buf, h2st, (__hip_bfloat16*)d_out, ctr);

    lin_softmax<<<dim3((TT * BB) / 64), dim3(256), 0, stream>>>(
        Wlinc, b_lin, (float*)d_out);
}

// Round 5
// 10908.174 us; speedup vs baseline: 3.3593x; 1.2930x over previous
//
#include <hip/hip_runtime.h>
#include <hip/hip_bf16.h>

// Problem constants
#define BB 128   // batch
#define TT 1024  // timesteps
#define HH 512   // hidden
#define VV 256   // vocab
#define NBLK 128 // 64 stage1 + 64 stage2 blocks (32 per batch-half each)

typedef __attribute__((ext_vector_type(8))) short short8;   // 8 x bf16
typedef __attribute__((ext_vector_type(4))) float floatx4;  // MFMA acc

union AFrag { unsigned long long u[2]; short8 s; };

__device__ __forceinline__ floatx4 mfma16(short8 a, short8 b, floatx4 c) {
    return __builtin_amdgcn_mfma_f32_16x16x32_bf16(a, b, c, 0, 0, 0);
}
__device__ __forceinline__ float sigm(float x) { return 1.0f / (1.0f + __expf(-x)); }
__device__ __forceinline__ float tanh_fast(float x) {
    return 2.0f / (1.0f + __expf(-2.0f * x)) - 1.0f;
}
__device__ __forceinline__ void vmcnt0() {
    asm volatile("s_waitcnt vmcnt(0)" ::: "memory");
}
// Relaxed agent-scope ops: MALL-coherent, NO cache writeback/invalidate.
__device__ __forceinline__ unsigned ald32(const unsigned* p) {
    return __hip_atomic_load(p, __ATOMIC_RELAXED, __HIP_MEMORY_SCOPE_AGENT);
}
__device__ __forceinline__ unsigned long long ald64(const unsigned long long* p) {
    return __hip_atomic_load(p, __ATOMIC_RELAXED, __HIP_MEMORY_SCOPE_AGENT);
}
__device__ __forceinline__ void ast32(unsigned* p, unsigned v) {
    __hip_atomic_store(p, v, __ATOMIC_RELAXED, __HIP_MEMORY_SCOPE_AGENT);
}

// Spin until all 32 flags of `line` >= tgt (lanes 0-31 poll; coalesced 1-line load).
__device__ __forceinline__ void poll1(const unsigned* line, unsigned tgt, int lane) {
    for (;;) {
        unsigned v = tgt;
        if (lane < 32) v = ald32(line + lane);
        if (__all((int)(v >= tgt))) return;
        __builtin_amdgcn_s_sleep(2);
    }
}
// Dual poll: lanes 0-31 check lineA>=tA, lanes 32-63 check lineB>=tB.
__device__ __forceinline__ void poll2(const unsigned* lineA, unsigned tA,
                                      const unsigned* lineB, unsigned tB, int lane) {
    const unsigned* p = (lane < 32) ? (lineA + lane) : (lineB + (lane - 32));
    const unsigned tgt = (lane < 32) ? tA : tB;
    for (;;) {
        unsigned v = ald32(p);
        if (__all((int)(v >= tgt))) return;
        __builtin_amdgcn_s_sleep(2);
    }
}

// One-shot canonicalization: fp32 weights -> bf16 ws copies; bias pre-sums; x transpose.
__global__ __launch_bounds__(256) void canon(
    const float* __restrict__ x,
    const float* __restrict__ Whh1, const float* __restrict__ Wih2,
    const float* __restrict__ Whh2, const float* __restrict__ Wlin,
    const float* __restrict__ bih1, const float* __restrict__ bhh1,
    const float* __restrict__ bih2, const float* __restrict__ bhh2,
    __hip_bfloat16* __restrict__ Whh1c, __hip_bfloat16* __restrict__ Wih2c,
    __hip_bfloat16* __restrict__ Whh2c, __hip_bfloat16* __restrict__ Wlinc,
    float* __restrict__ bsum1, float* __restrict__ bsum2,
    float* __restrict__ xT)
{
    const int tid = blockIdx.x * 256 + threadIdx.x;
    const int np  = gridDim.x * 256;
    for (int i = tid; i < 2048 * 512; i += np) {
        Whh1c[i] = __float2bfloat16(Whh1[i]);
        Wih2c[i] = __float2bfloat16(Wih2[i]);
        Whh2c[i] = __float2bfloat16(Whh2[i]);
    }
    for (int i = tid; i < 256 * 512; i += np) Wlinc[i] = __float2bfloat16(Wlin[i]);
    for (int i = tid; i < 2048; i += np) {
        bsum1[i] = bih1[i] + bhh1[i];
        bsum2[i] = bih2[i] + bhh2[i];
    }
    for (int i = tid; i < BB * TT; i += np) {
        int b = i >> 10, t = i & 1023;
        xT[t * BB + b] = x[i];
    }
}

// Persistent dataflow LSTM. 4 independent groups: {stage1,stage2} x {batch half}.
// Flags: 4 x 128B lines, flags[(stage*2+half)*32 + lb] = completed-step count.
// h1: full array (slot t+1 = h1(t)); unique addresses -> plain cached loads.
// h2: 4-deep ring (slot (t+1)&3 = h2(t)); reused addresses -> atomic loads.
// No __syncthreads and no atomic RMW in the steady-state loop.
__global__ __launch_bounds__(256, 1) void lstm_persist(
    const float* __restrict__ xT,              // [T][B] fp32
    const float* __restrict__ Wih1,            // [2048] fp32 (IN=1)
    const __hip_bfloat16* __restrict__ Whh1c,  // [2048,512] bf16
    const float* __restrict__ bsum1,           // [2048]
    const __hip_bfloat16* __restrict__ Wih2c,  // [2048,512] bf16
    const __hip_bfloat16* __restrict__ Whh2c,  // [2048,512] bf16
    const float* __restrict__ bsum2,           // [2048]
    unsigned* __restrict__ flags,              // [4][32] u32, line-packed
    unsigned* __restrict__ h2ring,             // [4][B*H/2] u32
    unsigned* __restrict__ h1all,              // [1025][B*H/2] u32
    __hip_bfloat16* __restrict__ h2slots)      // d_out as bf16 slots [B][T][H]
{
    extern __shared__ __hip_bfloat16 lds[];    // stage1: 64 KB; stage2: 128 KB
    __shared__ unsigned cnt[16];               // per-step wave-completion counters

    const int bid   = blockIdx.x;
    const int stage = bid >> 6;                // 0: layer1, 1: layer2
    const int half  = (bid >> 5) & 1;          // batch half
    const int lb    = bid & 31;
    const int j0    = lb * 16;                 // h-unit tile
    const int b0    = half * 64;               // batch tile
    const int w     = threadIdx.x >> 6;
    const int lane  = threadIdx.x & 63;
    const int q     = lane >> 4, ln = lane & 15;
    const int r0    = b0 + w * 16;

    unsigned* myflag       = flags + (stage * 2 + half) * 32 + lb;
    const unsigned* line1  = flags + half * 32;        // stage1 flags, this half
    const unsigned* line2  = flags + 64 + half * 32;   // stage2 flags, this half

    // ---- stage weights into LDS, fragment-permuted (once) ----
    {
        const __hip_bfloat16* S0 = (stage == 0) ? Whh1c : Wih2c;
        for (int idx = threadIdx.x; idx < 4096; idx += 256) {
            const int g = idx >> 10, kk = (idx >> 6) & 15, l = idx & 63;
            const int lnt = l & 15, qt = l >> 4;
            const size_t src = (size_t)(g * 512 + j0 + lnt) * 512 + kk * 32 + qt * 8;
            *(float4*)(lds + idx * 8) = *(const float4*)(S0 + src);
            if (stage == 1)
                *(float4*)(lds + 32768 + idx * 8) = *(const float4*)(Whh2c + src);
        }
    }
    if (threadIdx.x < 16) cnt[threadIdx.x] = 0;
    __syncthreads();   // weights + counters ready; last sync in this kernel

    // per-thread step-invariant epilogue constants
    float wv[4], bs[4];
    #pragma unroll
    for (int g = 0; g < 4; ++g) {
        const int j = g * 512 + j0 + ln;
        if (stage == 0) { wv[g] = Wih1[j]; bs[g] = bsum1[j]; }
        else            { wv[g] = 0.0f;    bs[g] = bsum2[j]; }
    }
    float cre[4] = {0.0f, 0.0f, 0.0f, 0.0f};   // register-resident cell state

    const __hip_bfloat16* h1bf = (const __hip_bfloat16*)h1all;
    const int aoff = (r0 + ln) * HH + q * 8;          // A-frag element offset
    const int au   = (r0 + ln) * 128 + q * 2;         // same, in u64 units
    const int jc   = j0 + (ln & ~1);                  // pack: even column of pair
    const int rA   = (ln & 1) ? 2 : 0;

    for (int t = 0; t < TT; ++t) {
        floatx4 acc[4];
        #pragma unroll
        for (int g = 0; g < 4; ++g) acc[g] = floatx4{0, 0, 0, 0};
        unsigned pk[4];

        if (stage == 0) {
            if (t > 0) poll1(line1, (unsigned)t, lane);   // own group done t-1
            // h1(t-1) = slot t, plain cached dwordx4 loads (unique addresses)
            const __hip_bfloat16* hA = h1bf + (size_t)t * 65536;
            float4 xv4 = *(const float4*)(xT + t * BB + r0 + q * 4);
            AFrag A0[16];
            #pragma unroll
            for (int kk = 0; kk < 16; ++kk)
                A0[kk].s = *(const short8*)(hA + aoff + kk * 32);
            #pragma unroll
            for (int kk = 0; kk < 16; ++kk) {
                #pragma unroll
                for (int g = 0; g < 4; ++g)
                    acc[g] = mfma16(A0[kk].s,
                        *(const short8*)(lds + ((g * 16 + kk) * 64 + lane) * 8), acc[g]);
            }
            #pragma unroll
            for (int reg = 0; reg < 4; ++reg) {
                const float xv = ((const float*)&xv4)[reg];
                float gi = acc[0][reg] + xv * wv[0] + bs[0];
                float gf = acc[1][reg] + xv * wv[1] + bs[1];
                float gg = acc[2][reg] + xv * wv[2] + bs[2];
                float go = acc[3][reg] + xv * wv[3] + bs[3];
                float cn = sigm(gf) * cre[reg] + sigm(gi) * tanh_fast(gg);
                cre[reg] = cn;
                float hn = sigm(go) * tanh_fast(cn);
                __hip_bfloat16 hb = __float2bfloat16(hn);
                unsigned short us; __builtin_memcpy(&us, &hb, 2);
                unsigned mine = us;
                unsigned other = (unsigned)__shfl_xor((int)mine, 1, 64);
                pk[reg] = (ln & 1) ? ((other & 0xffffu) | (mine << 16))
                                   : ((mine & 0xffffu) | (other << 16));
            }
            const int bA = r0 + q * 4 + rA;
            unsigned* dst = h1all + (size_t)(t + 1) * 32768;    // h1(t) -> slot t+1
            ast32(dst + ((bA * HH + jc) >> 1),       pk[rA]);
            ast32(dst + (((bA + 1) * HH + jc) >> 1), pk[rA + 1]);
        } else {
            // stage2 step t computes h2(t) from h1(t) [slot t+1] and h2(t-1) [ring t&3]
            poll2(line1, (unsigned)(t + 1), line2, (unsigned)t, lane);
            const __hip_bfloat16* hA = h1bf + (size_t)(t + 1) * 65536;
            const unsigned long long* hB =
                (const unsigned long long*)h2ring + (size_t)(t & 3) * 16384;
            AFrag A0[16], A1[16];
            #pragma unroll
            for (int kk = 0; kk < 16; ++kk) {
                A0[kk].s    = *(const short8*)(hA + aoff + kk * 32);
                A1[kk].u[0] = ald64(hB + au + kk * 8);
                A1[kk].u[1] = ald64(hB + au + kk * 8 + 1);
            }
            #pragma unroll
            for (int kk = 0; kk < 16; ++kk) {
                #pragma unroll
                for (int g = 0; g < 4; ++g)
                    acc[g] = mfma16(A0[kk].s,
                        *(const short8*)(lds + ((g * 16 + kk) * 64 + lane) * 8), acc[g]);
            }
            #pragma unroll
            for (int kk = 0; kk < 16; ++kk) {
                #pragma unroll
                for (int g = 0; g < 4; ++g)
                    acc[g] = mfma16(A1[kk].s,
                        *(const short8*)(lds + 32768 + ((g * 16 + kk) * 64 + lane) * 8), acc[g]);
            }
            #pragma unroll
            for (int reg = 0; reg < 4; ++reg) {
                float gi = acc[0][reg] + bs[0];
                float gf = acc[1][reg] + bs[1];
                float gg = acc[2][reg] + bs[2];
                float go = acc[3][reg] + bs[3];
                float cn = sigm(gf) * cre[reg] + sigm(gi) * tanh_fast(gg);
                cre[reg] = cn;
                float hn = sigm(go) * tanh_fast(cn);
                __hip_bfloat16 hb = __float2bfloat16(hn);
                unsigned short us; __builtin_memcpy(&us, &hb, 2);
                unsigned mine = us;
                unsigned other = (unsigned)__shfl_xor((int)mine, 1, 64);
                pk[reg] = (ln & 1) ? ((other & 0xffffu) | (mine << 16))
                                   : ((mine & 0xffffu) | (other << 16));
            }
            const int bA = r0 + q * 4 + rA;
            unsigned* dst = h2ring + (size_t)((t + 1) & 3) * 32768; // h2(t)
            ast32(dst + ((bA * HH + jc) >> 1),       pk[rA]);
            ast32(dst + (((bA + 1) * HH + jc) >> 1), pk[rA + 1]);
            unsigned* outs = (unsigned*)h2slots;                    // plain cached
            outs[(((size_t)bA * TT + t) * HH + jc) >> 1]       = pk[rA];
            outs[(((size_t)(bA + 1) * TT + t) * HH + jc) >> 1] = pk[rA + 1];
        }

        // ---- publish: wait own-wave store acks, last wave of block sets flag ----
        vmcnt0();
        if ((threadIdx.x & 63) == 0) {
            unsigned old = atomicAdd(&cnt[t & 15], 1u);    // LDS atomic, block-local
            if (old == 3) {
                cnt[(t + 8) & 15] = 0;                     // recycle (skew <= 1 step)
                ast32(myflag, (unsigned)(t + 1));
            }
        }
    }
}

// In-place linear+softmax over all T*B rows (slot r: 512 bf16 -> 256 fp32).
__global__ __launch_bounds__(256) void lin_softmax(
    const __hip_bfloat16* __restrict__ Wlinc,  // [256,512] bf16
    const float* __restrict__ blin,            // [256] fp32
    float* out)                                // d_out; aliases the bf16 slots
{
    const __hip_bfloat16* slots = (const __hip_bfloat16*)out;
    const int w = threadIdx.x >> 6;
    const int lane = threadIdx.x & 63;
    const int q = lane >> 4, ln = lane & 15;
    const int r0 = blockIdx.x * 64 + w * 16;

    floatx4 acc[16];
    #pragma unroll
    for (int n = 0; n < 16; ++n) acc[n] = floatx4{0, 0, 0, 0};

    const size_t arow = (size_t)(r0 + ln) * HH + q * 8;
    #pragma unroll 4
    for (int kk = 0; kk < 16; ++kk) {
        short8 a = *(const short8*)(slots + arow + kk * 32);
        #pragma unroll
        for (int n = 0; n < 16; ++n) {
            short8 bf = *(const short8*)(Wlinc + (n * 16 + ln) * HH + kk * 32 + q * 8);
            acc[n] = mfma16(a, bf, acc[n]);
        }
    }

    float bl[16];
    #pragma unroll
    for (int n = 0; n < 16; ++n) bl[n] = blin[n * 16 + ln];

    #pragma unroll
    for (int reg = 0; reg < 4; ++reg) {
        float v[16];
        float mx = -3.4e38f;
        #pragma unroll
        for (int n = 0; n < 16; ++n) {
            v[n] = acc[n][reg] + bl[n];
            mx = fmaxf(mx, v[n]);
        }
        #pragma unroll
        for (int m = 1; m < 16; m <<= 1) mx = fmaxf(mx, __shfl_xor(mx, m));
        float sum = 0.0f;
        #pragma unroll
        for (int n = 0; n < 16; ++n) { v[n] = __expf(v[n] - mx); sum += v[n]; }
        #pragma unroll
        for (int m = 1; m < 16; m <<= 1) sum += __shfl_xor(sum, m);
        const float inv = 1.0f / sum;

        const int r = r0 + q * 4 + reg;        // r = b*T + t
        #pragma unroll
        for (int n = 0; n < 16; ++n)
            out[(size_t)r * VV + n * 16 + ln] = v[n] * inv;
    }
}

extern "C" void kernel_launch(void* const* d_in, const int* in_sizes, int n_in,
                              void* d_out, int out_size, void* d_ws, size_t ws_size,
                              hipStream_t stream)
{
    const float* x     = (const float*)d_in[0];
    const float* W_ih1 = (const float*)d_in[1];
    const float* W_hh1 = (const float*)d_in[2];
    const float* b_ih1 = (const float*)d_in[3];
    const float* b_hh1 = (const float*)d_in[4];
    const float* W_ih2 = (const float*)d_in[5];
    const float* W_hh2 = (const float*)d_in[6];
    const float* b_ih2 = (const float*)d_in[7];
    const float* b_hh2 = (const float*)d_in[8];
    const float* W_lin = (const float*)d_in[9];
    const float* b_lin = (const float*)d_in[10];

    char* p = (char*)d_ws;
    unsigned* flags  = (unsigned*)p;   p += 512;                      // 4 lines
    unsigned* h2ring = (unsigned*)p;   p += (size_t)4 * 131072;       // 512 KB
    unsigned* h1all  = (unsigned*)p;   p += (size_t)1025 * 131072;    // 128.1 MB
    const size_t zbytes = 512 + (size_t)4 * 131072 + 131072;          // flags+ring+slot0
    float* bsum1 = (float*)p;          p += 2048 * 4;
    float* bsum2 = (float*)p;          p += 2048 * 4;
    float* xT    = (float*)p;          p += (size_t)BB * TT * 4;
    __hip_bfloat16* Whh1c = (__hip_bfloat16*)p; p += (size_t)2048 * 512 * 2;
    __hip_bfloat16* Wih2c = (__hip_bfloat16*)p; p += (size_t)2048 * 512 * 2;
    __hip_bfloat16* Whh2c = (__hip_bfloat16*)p; p += (size_t)2048 * 512 * 2;
    __hip_bfloat16* Wlinc = (__hip_bfloat16*)p; p += (size_t)256 * 512 * 2;
    // total ws use ~141.7 MB (proven available in rounds 2-3)

    hipMemsetAsync(d_ws, 0, zbytes, stream);   // flags + h2 ring + h1 slot 0

    canon<<<dim3(512), dim3(256), 0, stream>>>(
        x, W_hh1, W_ih2, W_hh2, W_lin, b_ih1, b_hh1, b_ih2, b_hh2,
        Whh1c, Wih2c, Whh2c, Wlinc, bsum1, bsum2, xT);

    const int smem_bytes = 131072;   // 128 KB dynamic LDS
    (void)hipFuncSetAttribute((const void*)lstm_persist,
                              hipFuncAttributeMaxDynamicSharedMemorySize, smem_bytes);

    lstm_persist<<<dim3(NBLK), dim3(256), smem_bytes, stream>>>(
        xT, W_ih1, Whh1c, bsum1, Wih2c, Whh2c, bsum2,
        flags, h2ring, h1all, (__hip_bfloat16*)d_out);

    lin_softmax<<<dim3((TT * BB) / 64), dim3(256), 0, stream>>>(
        Wlinc, b_lin, (float*)d_out);
}